// Round 2
// baseline (156.646 us; speedup 1.0000x reference)
//
#include <hip/hip_runtime.h>

// ---------------------------------------------------------------------------
// DSTGCN fused pipeline, MI355X gfx950.
// Round 15 = round 14 with k_hyper rebuilt on 32-node tiles:
//   grid 512 -> 256 blocks (128 n-tiles x 2 o-halves, exactly 1 block/CU),
//   wpB L2 stream halves (256 MB -> 128 MB) since each b0/b1 fragment pair
//   now feeds TWO node-group mfma16 pairs. LDS 103 KB, 1 wave/SIMD (inner
//   loop is FMA-dense; unroll-2 prefetch covers L2 latency).
// k_prep / k_attn byte-identical to round 14.
// ---------------------------------------------------------------------------

using bf16x8 = __attribute__((ext_vector_type(8))) __bf16;
using f32x4  = __attribute__((ext_vector_type(4))) float;
using f32x16 = __attribute__((ext_vector_type(16))) float;
using u32x4  = __attribute__((ext_vector_type(4))) unsigned int;

__device__ __forceinline__ unsigned short f2bf_bits(float f) {
    unsigned int u = __float_as_uint(f);
    u += 0x7fffu + ((u >> 16) & 1u);          // RNE
    return (unsigned short)(u >> 16);
}

// pack two floats' high halves: lo16 = hi16(a), hi16 = hi16(b)  (bf16 trunc)
__device__ __forceinline__ unsigned int PK(float a, float b) {
    return __builtin_amdgcn_perm(__float_as_uint(b), __float_as_uint(a),
                                 0x07060302u);
}

__device__ __forceinline__ f32x4 mfma16(bf16x8 a, bf16x8 b, f32x4 c) {
    return __builtin_amdgcn_mfma_f32_16x16x32_bf16(a, b, c, 0, 0, 0);
}
__device__ __forceinline__ f32x16 mfma32(bf16x8 a, bf16x8 b, f32x16 c) {
    return __builtin_amdgcn_mfma_f32_32x32x16_bf16(a, b, c, 0, 0, 0);
}
__device__ __forceinline__ f32x16 zero16() {
    f32x16 z;
    #pragma unroll
    for (int i = 0; i < 16; ++i) z[i] = 0.f;
    return z;
}

// ---------------- k_prep: all preprocessing in one launch ------------------
// [0,1536)    : LN -> eT (16 rows/block, 4 rows/wave unrolled)
// [1536,1920) : x -> vT
// [1920,2944) : ne_bf
// [2944,3072) : wpB frag-linear
// block 3072  : biasw
__global__ __launch_bounds__(256) void k_prep(const float* __restrict__ x,
                                              const float* __restrict__ node_emb,
                                              const float* __restrict__ time_emb,
                                              const float* __restrict__ wp,
                                              const float* __restrict__ bias_pool,
                                              const float* __restrict__ gamma,
                                              const float* __restrict__ beta,
                                              unsigned short* __restrict__ eT,
                                              unsigned short* __restrict__ vT,
                                              unsigned short* __restrict__ ne_bf,
                                              unsigned short* __restrict__ wpB,
                                              float* __restrict__ biasw) {
    __shared__ float tile[64 * 65];
    const int b = blockIdx.x;
    const int t = threadIdx.x;
    if (b < 1536) {                               // ---- LayerNorm -> eT ----
        int lane = t & 63;
        int row0 = b * 16 + ((t >> 6) << 2);
        float gm = gamma[lane], bb2 = beta[lane];
        #pragma unroll
        for (int ri = 0; ri < 4; ++ri) {
            int rowf = row0 + ri;                 // bt*4096+n
            int bt = rowf >> 12, row = rowf & 4095;
            float v = node_emb[(row << 6) | lane] + time_emb[(bt << 6) | lane];
            float s = v, s2 = v * v;
            #pragma unroll
            for (int off = 32; off; off >>= 1) {
                s  += __shfl_xor(s,  off);
                s2 += __shfl_xor(s2, off);
            }
            float mu  = s * 0.015625f;
            float var = s2 * 0.015625f - mu * mu;
            float r   = rsqrtf(var + 1e-12f);
            float o   = (v - mu) * r * gm + bb2;
            size_t idx = (size_t)bt * 262144 + ((row >> 5) << 11)
                       + ((lane >> 4) << 9) + (((lane >> 3) & 1) << 8)
                       + ((row & 31) << 3) + (lane & 7);
            eT[idx] = f2bf_bits(o);
        }
    } else if (b < 1920) {                        // ---- x -> vT ----
        int bb = b - 1536;
        int bt = bb >> 6, n0 = (bb & 63) << 6;
        const float* xr = x + ((size_t)((bt << 12) | n0) << 6);
        #pragma unroll
        for (int it = 0; it < 16; ++it) {
            int i = (it << 2) + (t >> 6);
            int d = t & 63;
            tile[i * 65 + d] = xr[(i << 6) + d];  // coalesced 256B rows
        }
        __syncthreads();
        unsigned short* dst = vT + (size_t)bt * 262144;
        #pragma unroll
        for (int it = 0; it < 16; ++it) {
            int d = (it << 2) + (t >> 6);
            int n = t & 63;                       // key = n0 + n
            dst[(((n0 + n) >> 3) << 9) + (d << 3) + (n & 7)]
                = f2bf_bits(tile[n * 65 + d]);
        }
    } else if (b < 2944) {                        // ---- ne_bf ----
        int idx = (b - 1920) * 256 + t;
        ne_bf[idx] = f2bf_bits(node_emb[idx]);
    } else if (b < 3072) {                        // ---- wpB (frag-linear) ----
        int ki = b - 2944;
        #pragma unroll
        for (int it = 0; it < 16; ++it) {
            int d = (it << 2) + (t >> 6);
            int o = t & 63;
            tile[d * 65 + o] = wp[(d << 13) + (ki << 6) + o];
        }
        __syncthreads();
        unsigned short* dst = wpB + ((size_t)ki << 12);   // 4096 shorts / ki
        #pragma unroll
        for (int it = 0; it < 2; ++it) {
            int u    = (it << 8) + t;             // 0..511
            int ot   = u >> 7;
            int frag = (u >> 6) & 1;
            int pos  = u & 63;
            int quad = pos >> 4, l16 = pos & 15;
            unsigned short* dp = dst + ((((ot << 1) + frag) << 9) + (pos << 3));
            #pragma unroll
            for (int j = 0; j < 8; ++j)
                dp[j] = f2bf_bits(
                    tile[((frag << 5) + (quad << 3) + j) * 65 + (ot << 4) + l16]);
        }
    } else {                                      // ---- bias ----
        for (int idx = t; idx < 384; idx += 256) {
            int bt = idx >> 6, o = idx & 63;
            float bsum = 0.f;
            for (int d = 0; d < 64; ++d)
                bsum += time_emb[(bt << 6) + d] * bias_pool[(d << 6) + o];
            biasw[idx] = bsum;
        }
    }
}

// ---------------- k_attn: half-key flash attention, 64 q-rows/wave ---------
// Grid = 768 blocks of 4 waves. XCD-chunked swizzle: logical = (bid%8)*96 +
// bid/8; set = logical/64 -> (bt,half); qc = logical%64 -> 64-q chunk.
// Each wave owns keys [half*2048 + w*512, +512) and ALL 64 q rows of the
// chunk (two 32-row MFMA column sets) -> K/V bytes serve 2x the q rows.
__global__ __launch_bounds__(256, 2) void k_attn(const unsigned short* __restrict__ eT,
                                                 const unsigned short* __restrict__ vT,
                                                 float* __restrict__ P0,
                                                 float* __restrict__ P1,
                                                 float* __restrict__ L0,
                                                 float* __restrict__ L1) {
    __shared__ __align__(16) float Obuf[2][64 * 68];   // 34.8 KB merge buffers
    __shared__ float l_s[4][64];
    const int tid  = threadIdx.x;
    const int w    = tid >> 6;
    const int lane = tid & 63;
    const int l32  = lane & 31;
    const int h    = lane >> 5;

    const int bid     = (int)blockIdx.x;
    const int logical = (bid & 7) * 96 + (bid >> 3);   // bijective, 768%8==0
    const int set     = logical >> 6;                  // 0..11 = (bt,half)
    const int qc      = logical & 63;
    const int bt      = set >> 1;
    const int half    = set & 1;
    const int qbase   = qc << 6;                       // 64 q rows

    const unsigned short* eb = eT + (size_t)bt * 262144;
    const unsigned short* vb = vT + (size_t)bt * 262144;
    float* Pout = half ? P1 : P0;
    float* Lout = half ? L1 : L0;

    const unsigned short* qp = eb + ((qbase >> 5) << 11) + (h << 8) + (l32 << 3);
    bf16x8 qf0[4], qf1[4];
    #pragma unroll
    for (int c = 0; c < 4; ++c) {
        bf16x8 q0 = *(const bf16x8*)(qp + (c << 9));
        bf16x8 q1 = *(const bf16x8*)(qp + 2048 + (c << 9));
        #pragma unroll
        for (int j = 0; j < 8; ++j) {
            q0[j] = (__bf16)((float)q0[j] * 1.44269504f);
            q1[j] = (__bf16)((float)q1[j] * 1.44269504f);
        }
        qf0[c] = q0;
        qf1[c] = q1;
    }

    f32x16 O00 = zero16(), O01 = zero16();   // q-set 0, d 0-31 / 32-63
    f32x16 O10 = zero16(), O11 = zero16();   // q-set 1
    float lsa0[4] = {0.f, 0.f, 0.f, 0.f};
    float lsa1[4] = {0.f, 0.f, 0.f, 0.f};

    const int kstart = (half << 11) + (w << 9);  // 512 keys per wave
    const unsigned short* krBase = eb + ((kstart >> 5) << 11) + (h << 8) + (l32 << 3);
    const unsigned short* vrBase = vb + ((kstart >> 3) << 9) + (h << 9) + (l32 << 3);

    bf16x8 kA0, kA1, kA2, kA3, vA0, vA1, vA2, vA3;
    bf16x8 kB0, kB1, kB2, kB3, vB0, vB1, vB2, vB3;

#define LOAD_GRP(gi, K0, K1, K2, K3, V0, V1, V2, V3)                    \
    {                                                                   \
        const unsigned short* kp = krBase + ((gi) << 11);               \
        const unsigned short* vp = vrBase + ((gi) << 11);               \
        K0 = *(const bf16x8*)(kp);                                      \
        K1 = *(const bf16x8*)(kp + 512);                                \
        K2 = *(const bf16x8*)(kp + 1024);                               \
        K3 = *(const bf16x8*)(kp + 1536);                               \
        V0 = *(const bf16x8*)(vp);                                      \
        V1 = *(const bf16x8*)(vp + 256);                                \
        V2 = *(const bf16x8*)(vp + 1024);                               \
        V3 = *(const bf16x8*)(vp + 1280);                               \
    }

#define QSET(QF, LSA, OA, OB, K0, K1, K2, K3, V0, V1, V2, V3)           \
    {                                                                   \
        f32x16 S = zero16();                                            \
        S = mfma32(K0, QF[0], S);                                       \
        S = mfma32(K1, QF[1], S);                                       \
        S = mfma32(K2, QF[2], S);                                       \
        S = mfma32(K3, QF[3], S);                                       \
        float p[16];                                                    \
        _Pragma("unroll")                                               \
        for (int r = 0; r < 16; ++r) p[r] = __builtin_amdgcn_exp2f(S[r]); \
        _Pragma("unroll")                                               \
        for (int r = 0; r < 4; ++r)                                     \
            LSA[r] += (p[r] + p[r + 4]) + (p[r + 8] + p[r + 12]);       \
        unsigned int Pa = PK(p[0], p[1]),   Pb = PK(p[2], p[3]);        \
        unsigned int Pc = PK(p[4], p[5]),   Pd = PK(p[6], p[7]);        \
        unsigned int Pe = PK(p[8], p[9]),   Pf = PK(p[10], p[11]);      \
        unsigned int Pg = PK(p[12], p[13]), Ph = PK(p[14], p[15]);      \
        unsigned int e0 = (unsigned int)__shfl_xor((int)(h ? Pa : Pc), 32); \
        unsigned int e1 = (unsigned int)__shfl_xor((int)(h ? Pb : Pd), 32); \
        unsigned int e2 = (unsigned int)__shfl_xor((int)(h ? Pe : Pg), 32); \
        unsigned int e3 = (unsigned int)__shfl_xor((int)(h ? Pf : Ph), 32); \
        u32x4 w0 = { h ? e0 : Pa, h ? e1 : Pb,                          \
                     h ? Pc : e0, h ? Pd : e1 };                        \
        u32x4 w1 = { h ? e2 : Pe, h ? e3 : Pf,                          \
                     h ? Pg : e2, h ? Ph : e3 };                        \
        bf16x8 pf0 = __builtin_bit_cast(bf16x8, w0);                    \
        bf16x8 pf1 = __builtin_bit_cast(bf16x8, w1);                    \
        OA = mfma32(pf0, V0, OA);                                       \
        OB = mfma32(pf0, V1, OB);                                       \
        OA = mfma32(pf1, V2, OA);                                       \
        OB = mfma32(pf1, V3, OB);                                       \
    }

#define COMPUTE_GRP(K0, K1, K2, K3, V0, V1, V2, V3)                     \
    QSET(qf0, lsa0, O00, O01, K0, K1, K2, K3, V0, V1, V2, V3)           \
    QSET(qf1, lsa1, O10, O11, K0, K1, K2, K3, V0, V1, V2, V3)

    LOAD_GRP(0, kA0, kA1, kA2, kA3, vA0, vA1, vA2, vA3);
    for (int gi = 0; gi < 14; gi += 2) {
        LOAD_GRP(gi + 1, kB0, kB1, kB2, kB3, vB0, vB1, vB2, vB3);
        COMPUTE_GRP(kA0, kA1, kA2, kA3, vA0, vA1, vA2, vA3);
        LOAD_GRP(gi + 2, kA0, kA1, kA2, kA3, vA0, vA1, vA2, vA3);
        COMPUTE_GRP(kB0, kB1, kB2, kB3, vB0, vB1, vB2, vB3);
    }
    LOAD_GRP(15, kB0, kB1, kB2, kB3, vB0, vB1, vB2, vB3);
    COMPUTE_GRP(kA0, kA1, kA2, kA3, vA0, vA1, vA2, vA3);
    COMPUTE_GRP(kB0, kB1, kB2, kB3, vB0, vB1, vB2, vB3);
#undef LOAD_GRP
#undef QSET
#undef COMPUTE_GRP

    float ls0 = (lsa0[0] + lsa0[1]) + (lsa0[2] + lsa0[3]);
    float ls1 = (lsa1[0] + lsa1[1]) + (lsa1[2] + lsa1[3]);
    float l2_0 = ls0 + __shfl_xor(ls0, 32);
    float l2_1 = ls1 + __shfl_xor(ls1, 32);
    if (h == 0) {
        l_s[w][l32]      = l2_0;
        l_s[w][l32 + 32] = l2_1;
    }
    float* buf = Obuf[w & 1];
    if (w < 2) {
        #pragma unroll
        for (int r = 0; r < 16; ++r) {
            int qrow = (r & 3) + ((r >> 2) << 3) + (h << 2);
            buf[qrow * 68 + l32]             = O00[r];
            buf[qrow * 68 + 32 + l32]        = O01[r];
            buf[(qrow + 32) * 68 + l32]      = O10[r];
            buf[(qrow + 32) * 68 + 32 + l32] = O11[r];
        }
    }
    __syncthreads();
    if (w >= 2) {
        #pragma unroll
        for (int r = 0; r < 16; ++r) {
            int qrow = (r & 3) + ((r >> 2) << 3) + (h << 2);
            buf[qrow * 68 + l32]             += O00[r];
            buf[qrow * 68 + 32 + l32]        += O01[r];
            buf[(qrow + 32) * 68 + l32]      += O10[r];
            buf[(qrow + 32) * 68 + 32 + l32] += O11[r];
        }
    }
    __syncthreads();
    {
        int q0 = tid >> 3;
        int d0 = (tid & 7) << 3;
        #pragma unroll
        for (int qh = 0; qh < 2; ++qh) {
            int q = q0 + (qh << 5);
            const float* b0 = Obuf[0] + q * 68 + d0;
            const float* b1 = Obuf[1] + q * 68 + d0;
            float* dst = Pout + (((size_t)(bt << 12) + qbase + q) << 6) + d0;
            #pragma unroll
            for (int i = 0; i < 8; ++i) dst[i] = b0[i] + b1[i];
            if ((tid & 7) == 0)
                Lout[(bt << 12) + qbase + q] =
                    l_s[0][q] + l_s[1][q] + l_s[2][q] + l_s[3][q];
        }
    }
}

// ---------------- k_hyper: fused hypernetwork contraction, 32-node tiles ---
// Grid = 256 blocks (128 n-tiles x 2 o-halves) = exactly 1 block/CU.
// Each wpB fragment pair (b0,b1) feeds TWO node-group mfma16 pairs ->
// wpB L2 stream halves vs the 16-node version (256 MB -> 128 MB).
__global__ __launch_bounds__(256, 1) void k_hyper(const float* __restrict__ x,
                                                  const float* __restrict__ P0,
                                                  const float* __restrict__ P1,
                                                  const float* __restrict__ L0,
                                                  const float* __restrict__ L1,
                                                  const unsigned short* __restrict__ ne_bf,
                                                  const unsigned short* __restrict__ wpB,
                                                  const float* __restrict__ bias_ws,
                                                  float* __restrict__ out) {
    __shared__ float smem[26112];          // 104.4 KB: xg (4x6176) then red (4x6528)
    __shared__ float invl_s[192];
    const int t    = threadIdx.x;
    const int w    = t >> 6;
    const int lane = t & 63;
    const int l16  = lane & 15;
    const int quad = lane >> 4;
    const int n0   = (blockIdx.x >> 1) << 5;   // 32-node tile
    const int oh   = blockIdx.x & 1;           // o-half

    if (t < 192) {
        int bt = t % 6, nl = t / 6;
        int idx = (bt << 12) + n0 + nl;
        invl_s[t] = 1.f / (L0[idx] + L1[idx]);
    }
    __syncthreads();

    float* xg_s = smem + w * 6176;             // 32 kk x (192 btnl + 1 pad)
    const int i0 = (w & 1) << 5;
    #pragma unroll 4
    for (int it = 0; it < 96; ++it) {
        int j  = (it << 6) + lane;             // 0..6143
        int kk = j & 31;
        int btnl = j >> 5;                     // 0..191 = nl*6+bt
        int bt = btnl % 6;
        int nl = btnl / 6;
        size_t idx = (((size_t)(bt << 12) + n0 + nl) << 6) + i0 + kk;
        float v;
        if (w < 2) v = x[idx];
        else       v = (P0[idx] + P1[idx]) * invl_s[btnl];
        xg_s[kk * 193 + btnl] = v;
    }
    __syncthreads();

    const unsigned short* nb = ne_bf + ((n0 + l16) << 6) + (quad << 3);
    bf16x8 a00 = *(const bf16x8*)(nb);
    bf16x8 a01 = *(const bf16x8*)(nb + 32);
    const unsigned short* nb1 = nb + (16 << 6);    // node group 1 (+16 nodes)
    bf16x8 a10 = *(const bf16x8*)(nb1);
    bf16x8 a11 = *(const bf16x8*)(nb1 + 32);

    float oac[2][2][4][6];                     // [g][oc][r][bt]
    #pragma unroll
    for (int g = 0; g < 2; ++g)
        #pragma unroll
        for (int oc = 0; oc < 2; ++oc)
            #pragma unroll
            for (int r = 0; r < 4; ++r)
                #pragma unroll
                for (int bt = 0; bt < 6; ++bt) oac[g][oc][r][bt] = 0.f;

    const int ki_base = w << 5;
    #pragma unroll 2
    for (int kk = 0; kk < 32; ++kk) {
        const int ki = ki_base + kk;
        float g0[4][6], g1[4][6];
        #pragma unroll
        for (int r = 0; r < 4; ++r) {
            const float* gp0 = xg_s + kk * 193 + ((quad << 2) + r) * 6;
            const float* gp1 = gp0 + 96;       // node group 1
            #pragma unroll
            for (int bt = 0; bt < 6; ++bt) {
                g0[r][bt] = gp0[bt];
                g1[r][bt] = gp1[bt];
            }
        }
        #pragma unroll
        for (int oc = 0; oc < 2; ++oc) {
            const unsigned short* bp =
                wpB + ((((size_t)ki << 2) + (oh * 2 + oc)) << 10) + (lane << 3);
            bf16x8 b0 = *(const bf16x8*)(bp);
            bf16x8 b1 = *(const bf16x8*)(bp + 512);
            f32x4 wf0 = mfma16(a00, b0, f32x4{0.f, 0.f, 0.f, 0.f});
            wf0 = mfma16(a01, b1, wf0);
            f32x4 wf1 = mfma16(a10, b0, f32x4{0.f, 0.f, 0.f, 0.f});
            wf1 = mfma16(a11, b1, wf1);
            #pragma unroll
            for (int r = 0; r < 4; ++r)
                #pragma unroll
                for (int bt = 0; bt < 6; ++bt) {
                    oac[0][oc][r][bt] += wf0[r] * g0[r][bt];
                    oac[1][oc][r][bt] += wf1[r] * g1[r][bt];
                }
        }
    }

    __syncthreads();                        // xg_s dead; smem becomes red
    #pragma unroll
    for (int g = 0; g < 2; ++g)
        #pragma unroll
        for (int oc = 0; oc < 2; ++oc)
            #pragma unroll
            for (int r = 0; r < 4; ++r)
                #pragma unroll
                for (int bt = 0; bt < 6; ++bt)
                    smem[w * 6528 + ((g << 4) + (quad << 2) + r) * 204
                         + bt * 34 + (oc << 4) + l16] = oac[g][oc][r][bt];
    __syncthreads();
    #pragma unroll
    for (int rr = 0; rr < 8; ++rr) {
        int nl = (w << 3) + rr;
        #pragma unroll
        for (int bp2 = 0; bp2 < 3; ++bp2) {
            int bt = bp2 * 2 + (lane >> 5);
            int ol = lane & 31;
            int o  = (oh << 5) + ol;
            int a  = nl * 204 + bt * 34 + ol;
            float v = smem[a] + smem[a + 6528] + smem[a + 13056] + smem[a + 19584]
                    + bias_ws[(bt << 6) + o];
            out[(((size_t)(bt << 12) + n0 + nl) << 6) + o] = v;
        }
    }
}

// ---------------------------------------------------------------------------
extern "C" void kernel_launch(void* const* d_in, const int* in_sizes, int n_in,
                              void* d_out, int out_size, void* d_ws, size_t ws_size,
                              hipStream_t stream) {
    const float* x         = (const float*)d_in[0];
    const float* node_emb  = (const float*)d_in[1];
    const float* time_emb  = (const float*)d_in[2];
    const float* wp        = (const float*)d_in[3];
    const float* bias_pool = (const float*)d_in[4];
    const float* gamma     = (const float*)d_in[5];
    const float* beta      = (const float*)d_in[6];
    float* out = (float*)d_out;

    char* wsb = (char*)d_ws;
    unsigned short* eT    = (unsigned short*)(wsb);                  // 3 MB
    unsigned short* vT    = (unsigned short*)(wsb + 3145728);        // 3 MB
    float*          P0    = (float*)         (wsb + 6291456);        // 6.3 MB
    float*          P1    = (float*)         (wsb + 12582912);       // 6.3 MB
    unsigned short* wpB   = (unsigned short*)(wsb + 18874368);       // 1 MB
    unsigned short* ne_bf = (unsigned short*)(wsb + 19922944);       // 0.5 MB
    float*          biasw = (float*)         (wsb + 20447232);       // 1.5 KB
    float*          L0    = (float*)         (wsb + 20448768);       // 96 KB
    float*          L1    = (float*)         (wsb + 20547072);       // 96 KB

    k_prep<<<3073, 256, 0, stream>>>(x, node_emb, time_emb, wp, bias_pool,
                                     gamma, beta, eT, vT, ne_bf, wpB, biasw);
    k_attn<<<768, 256, 0, stream>>>(eT, vT, P0, P1, L0, L1);
    k_hyper<<<256, 256, 0, stream>>>(x, P0, P1, L0, L1, ne_bf, wpB, biasw, out);
}

// Round 3
// 139.000 us; speedup vs baseline: 1.1270x; 1.1270x over previous
//
#include <hip/hip_runtime.h>

// ---------------------------------------------------------------------------
// DSTGCN fused pipeline, MI355X gfx950.
// Round 16 = round 14 geometry for k_hyper (16-node tiles, 512 blocks) with
// the latency fixes the r15 counters demanded (MfmaUtil 2.9 / VALUBusy 12.5 /
// Occ 10% = pure latency-bound):
//   (a) stage loads float4 (was scalar f32: 4x fewer global ops),
//   (b) explicit double-buffered wpB fragment prefetch in the kk loop,
//   (c) __launch_bounds__(256,3) -> 3 blocks/CU (LDS 52.7 KB x 3 fits 160 KB).
// k_prep / k_attn byte-identical to round 14/15.
// ---------------------------------------------------------------------------

using bf16x8 = __attribute__((ext_vector_type(8))) __bf16;
using f32x4  = __attribute__((ext_vector_type(4))) float;
using f32x16 = __attribute__((ext_vector_type(16))) float;
using u32x4  = __attribute__((ext_vector_type(4))) unsigned int;

__device__ __forceinline__ unsigned short f2bf_bits(float f) {
    unsigned int u = __float_as_uint(f);
    u += 0x7fffu + ((u >> 16) & 1u);          // RNE
    return (unsigned short)(u >> 16);
}

// pack two floats' high halves: lo16 = hi16(a), hi16 = hi16(b)  (bf16 trunc)
__device__ __forceinline__ unsigned int PK(float a, float b) {
    return __builtin_amdgcn_perm(__float_as_uint(b), __float_as_uint(a),
                                 0x07060302u);
}

__device__ __forceinline__ f32x4 mfma16(bf16x8 a, bf16x8 b, f32x4 c) {
    return __builtin_amdgcn_mfma_f32_16x16x32_bf16(a, b, c, 0, 0, 0);
}
__device__ __forceinline__ f32x16 mfma32(bf16x8 a, bf16x8 b, f32x16 c) {
    return __builtin_amdgcn_mfma_f32_32x32x16_bf16(a, b, c, 0, 0, 0);
}
__device__ __forceinline__ f32x16 zero16() {
    f32x16 z;
    #pragma unroll
    for (int i = 0; i < 16; ++i) z[i] = 0.f;
    return z;
}

// ---------------- k_prep: all preprocessing in one launch ------------------
// [0,1536)    : LN -> eT (16 rows/block, 4 rows/wave unrolled)
// [1536,1920) : x -> vT
// [1920,2944) : ne_bf
// [2944,3072) : wpB frag-linear
// block 3072  : biasw
__global__ __launch_bounds__(256) void k_prep(const float* __restrict__ x,
                                              const float* __restrict__ node_emb,
                                              const float* __restrict__ time_emb,
                                              const float* __restrict__ wp,
                                              const float* __restrict__ bias_pool,
                                              const float* __restrict__ gamma,
                                              const float* __restrict__ beta,
                                              unsigned short* __restrict__ eT,
                                              unsigned short* __restrict__ vT,
                                              unsigned short* __restrict__ ne_bf,
                                              unsigned short* __restrict__ wpB,
                                              float* __restrict__ biasw) {
    __shared__ float tile[64 * 65];
    const int b = blockIdx.x;
    const int t = threadIdx.x;
    if (b < 1536) {                               // ---- LayerNorm -> eT ----
        int lane = t & 63;
        int row0 = b * 16 + ((t >> 6) << 2);
        float gm = gamma[lane], bb2 = beta[lane];
        #pragma unroll
        for (int ri = 0; ri < 4; ++ri) {
            int rowf = row0 + ri;                 // bt*4096+n
            int bt = rowf >> 12, row = rowf & 4095;
            float v = node_emb[(row << 6) | lane] + time_emb[(bt << 6) | lane];
            float s = v, s2 = v * v;
            #pragma unroll
            for (int off = 32; off; off >>= 1) {
                s  += __shfl_xor(s,  off);
                s2 += __shfl_xor(s2, off);
            }
            float mu  = s * 0.015625f;
            float var = s2 * 0.015625f - mu * mu;
            float r   = rsqrtf(var + 1e-12f);
            float o   = (v - mu) * r * gm + bb2;
            size_t idx = (size_t)bt * 262144 + ((row >> 5) << 11)
                       + ((lane >> 4) << 9) + (((lane >> 3) & 1) << 8)
                       + ((row & 31) << 3) + (lane & 7);
            eT[idx] = f2bf_bits(o);
        }
    } else if (b < 1920) {                        // ---- x -> vT ----
        int bb = b - 1536;
        int bt = bb >> 6, n0 = (bb & 63) << 6;
        const float* xr = x + ((size_t)((bt << 12) | n0) << 6);
        #pragma unroll
        for (int it = 0; it < 16; ++it) {
            int i = (it << 2) + (t >> 6);
            int d = t & 63;
            tile[i * 65 + d] = xr[(i << 6) + d];  // coalesced 256B rows
        }
        __syncthreads();
        unsigned short* dst = vT + (size_t)bt * 262144;
        #pragma unroll
        for (int it = 0; it < 16; ++it) {
            int d = (it << 2) + (t >> 6);
            int n = t & 63;                       // key = n0 + n
            dst[(((n0 + n) >> 3) << 9) + (d << 3) + (n & 7)]
                = f2bf_bits(tile[n * 65 + d]);
        }
    } else if (b < 2944) {                        // ---- ne_bf ----
        int idx = (b - 1920) * 256 + t;
        ne_bf[idx] = f2bf_bits(node_emb[idx]);
    } else if (b < 3072) {                        // ---- wpB (frag-linear) ----
        int ki = b - 2944;
        #pragma unroll
        for (int it = 0; it < 16; ++it) {
            int d = (it << 2) + (t >> 6);
            int o = t & 63;
            tile[d * 65 + o] = wp[(d << 13) + (ki << 6) + o];
        }
        __syncthreads();
        unsigned short* dst = wpB + ((size_t)ki << 12);   // 4096 shorts / ki
        #pragma unroll
        for (int it = 0; it < 2; ++it) {
            int u    = (it << 8) + t;             // 0..511
            int ot   = u >> 7;
            int frag = (u >> 6) & 1;
            int pos  = u & 63;
            int quad = pos >> 4, l16 = pos & 15;
            unsigned short* dp = dst + ((((ot << 1) + frag) << 9) + (pos << 3));
            #pragma unroll
            for (int j = 0; j < 8; ++j)
                dp[j] = f2bf_bits(
                    tile[((frag << 5) + (quad << 3) + j) * 65 + (ot << 4) + l16]);
        }
    } else {                                      // ---- bias ----
        for (int idx = t; idx < 384; idx += 256) {
            int bt = idx >> 6, o = idx & 63;
            float bsum = 0.f;
            for (int d = 0; d < 64; ++d)
                bsum += time_emb[(bt << 6) + d] * bias_pool[(d << 6) + o];
            biasw[idx] = bsum;
        }
    }
}

// ---------------- k_attn: half-key flash attention, 64 q-rows/wave ---------
// Grid = 768 blocks of 4 waves. XCD-chunked swizzle: logical = (bid%8)*96 +
// bid/8; set = logical/64 -> (bt,half); qc = logical%64 -> 64-q chunk.
// Each wave owns keys [half*2048 + w*512, +512) and ALL 64 q rows of the
// chunk (two 32-row MFMA column sets) -> K/V bytes serve 2x the q rows.
__global__ __launch_bounds__(256, 2) void k_attn(const unsigned short* __restrict__ eT,
                                                 const unsigned short* __restrict__ vT,
                                                 float* __restrict__ P0,
                                                 float* __restrict__ P1,
                                                 float* __restrict__ L0,
                                                 float* __restrict__ L1) {
    __shared__ __align__(16) float Obuf[2][64 * 68];   // 34.8 KB merge buffers
    __shared__ float l_s[4][64];
    const int tid  = threadIdx.x;
    const int w    = tid >> 6;
    const int lane = tid & 63;
    const int l32  = lane & 31;
    const int h    = lane >> 5;

    const int bid     = (int)blockIdx.x;
    const int logical = (bid & 7) * 96 + (bid >> 3);   // bijective, 768%8==0
    const int set     = logical >> 6;                  // 0..11 = (bt,half)
    const int qc      = logical & 63;
    const int bt      = set >> 1;
    const int half    = set & 1;
    const int qbase   = qc << 6;                       // 64 q rows

    const unsigned short* eb = eT + (size_t)bt * 262144;
    const unsigned short* vb = vT + (size_t)bt * 262144;
    float* Pout = half ? P1 : P0;
    float* Lout = half ? L1 : L0;

    const unsigned short* qp = eb + ((qbase >> 5) << 11) + (h << 8) + (l32 << 3);
    bf16x8 qf0[4], qf1[4];
    #pragma unroll
    for (int c = 0; c < 4; ++c) {
        bf16x8 q0 = *(const bf16x8*)(qp + (c << 9));
        bf16x8 q1 = *(const bf16x8*)(qp + 2048 + (c << 9));
        #pragma unroll
        for (int j = 0; j < 8; ++j) {
            q0[j] = (__bf16)((float)q0[j] * 1.44269504f);
            q1[j] = (__bf16)((float)q1[j] * 1.44269504f);
        }
        qf0[c] = q0;
        qf1[c] = q1;
    }

    f32x16 O00 = zero16(), O01 = zero16();   // q-set 0, d 0-31 / 32-63
    f32x16 O10 = zero16(), O11 = zero16();   // q-set 1
    float lsa0[4] = {0.f, 0.f, 0.f, 0.f};
    float lsa1[4] = {0.f, 0.f, 0.f, 0.f};

    const int kstart = (half << 11) + (w << 9);  // 512 keys per wave
    const unsigned short* krBase = eb + ((kstart >> 5) << 11) + (h << 8) + (l32 << 3);
    const unsigned short* vrBase = vb + ((kstart >> 3) << 9) + (h << 9) + (l32 << 3);

    bf16x8 kA0, kA1, kA2, kA3, vA0, vA1, vA2, vA3;
    bf16x8 kB0, kB1, kB2, kB3, vB0, vB1, vB2, vB3;

#define LOAD_GRP(gi, K0, K1, K2, K3, V0, V1, V2, V3)                    \
    {                                                                   \
        const unsigned short* kp = krBase + ((gi) << 11);               \
        const unsigned short* vp = vrBase + ((gi) << 11);               \
        K0 = *(const bf16x8*)(kp);                                      \
        K1 = *(const bf16x8*)(kp + 512);                                \
        K2 = *(const bf16x8*)(kp + 1024);                               \
        K3 = *(const bf16x8*)(kp + 1536);                               \
        V0 = *(const bf16x8*)(vp);                                      \
        V1 = *(const bf16x8*)(vp + 256);                                \
        V2 = *(const bf16x8*)(vp + 1024);                               \
        V3 = *(const bf16x8*)(vp + 1280);                               \
    }

#define QSET(QF, LSA, OA, OB, K0, K1, K2, K3, V0, V1, V2, V3)           \
    {                                                                   \
        f32x16 S = zero16();                                            \
        S = mfma32(K0, QF[0], S);                                       \
        S = mfma32(K1, QF[1], S);                                       \
        S = mfma32(K2, QF[2], S);                                       \
        S = mfma32(K3, QF[3], S);                                       \
        float p[16];                                                    \
        _Pragma("unroll")                                               \
        for (int r = 0; r < 16; ++r) p[r] = __builtin_amdgcn_exp2f(S[r]); \
        _Pragma("unroll")                                               \
        for (int r = 0; r < 4; ++r)                                     \
            LSA[r] += (p[r] + p[r + 4]) + (p[r + 8] + p[r + 12]);       \
        unsigned int Pa = PK(p[0], p[1]),   Pb = PK(p[2], p[3]);        \
        unsigned int Pc = PK(p[4], p[5]),   Pd = PK(p[6], p[7]);        \
        unsigned int Pe = PK(p[8], p[9]),   Pf = PK(p[10], p[11]);      \
        unsigned int Pg = PK(p[12], p[13]), Ph = PK(p[14], p[15]);      \
        unsigned int e0 = (unsigned int)__shfl_xor((int)(h ? Pa : Pc), 32); \
        unsigned int e1 = (unsigned int)__shfl_xor((int)(h ? Pb : Pd), 32); \
        unsigned int e2 = (unsigned int)__shfl_xor((int)(h ? Pe : Pg), 32); \
        unsigned int e3 = (unsigned int)__shfl_xor((int)(h ? Pf : Ph), 32); \
        u32x4 w0 = { h ? e0 : Pa, h ? e1 : Pb,                          \
                     h ? Pc : e0, h ? Pd : e1 };                        \
        u32x4 w1 = { h ? e2 : Pe, h ? e3 : Pf,                          \
                     h ? Pg : e2, h ? Ph : e3 };                        \
        bf16x8 pf0 = __builtin_bit_cast(bf16x8, w0);                    \
        bf16x8 pf1 = __builtin_bit_cast(bf16x8, w1);                    \
        OA = mfma32(pf0, V0, OA);                                       \
        OB = mfma32(pf0, V1, OB);                                       \
        OA = mfma32(pf1, V2, OA);                                       \
        OB = mfma32(pf1, V3, OB);                                       \
    }

#define COMPUTE_GRP(K0, K1, K2, K3, V0, V1, V2, V3)                     \
    QSET(qf0, lsa0, O00, O01, K0, K1, K2, K3, V0, V1, V2, V3)           \
    QSET(qf1, lsa1, O10, O11, K0, K1, K2, K3, V0, V1, V2, V3)

    LOAD_GRP(0, kA0, kA1, kA2, kA3, vA0, vA1, vA2, vA3);
    for (int gi = 0; gi < 14; gi += 2) {
        LOAD_GRP(gi + 1, kB0, kB1, kB2, kB3, vB0, vB1, vB2, vB3);
        COMPUTE_GRP(kA0, kA1, kA2, kA3, vA0, vA1, vA2, vA3);
        LOAD_GRP(gi + 2, kA0, kA1, kA2, kA3, vA0, vA1, vA2, vA3);
        COMPUTE_GRP(kB0, kB1, kB2, kB3, vB0, vB1, vB2, vB3);
    }
    LOAD_GRP(15, kB0, kB1, kB2, kB3, vB0, vB1, vB2, vB3);
    COMPUTE_GRP(kA0, kA1, kA2, kA3, vA0, vA1, vA2, vA3);
    COMPUTE_GRP(kB0, kB1, kB2, kB3, vB0, vB1, vB2, vB3);
#undef LOAD_GRP
#undef QSET
#undef COMPUTE_GRP

    float ls0 = (lsa0[0] + lsa0[1]) + (lsa0[2] + lsa0[3]);
    float ls1 = (lsa1[0] + lsa1[1]) + (lsa1[2] + lsa1[3]);
    float l2_0 = ls0 + __shfl_xor(ls0, 32);
    float l2_1 = ls1 + __shfl_xor(ls1, 32);
    if (h == 0) {
        l_s[w][l32]      = l2_0;
        l_s[w][l32 + 32] = l2_1;
    }
    float* buf = Obuf[w & 1];
    if (w < 2) {
        #pragma unroll
        for (int r = 0; r < 16; ++r) {
            int qrow = (r & 3) + ((r >> 2) << 3) + (h << 2);
            buf[qrow * 68 + l32]             = O00[r];
            buf[qrow * 68 + 32 + l32]        = O01[r];
            buf[(qrow + 32) * 68 + l32]      = O10[r];
            buf[(qrow + 32) * 68 + 32 + l32] = O11[r];
        }
    }
    __syncthreads();
    if (w >= 2) {
        #pragma unroll
        for (int r = 0; r < 16; ++r) {
            int qrow = (r & 3) + ((r >> 2) << 3) + (h << 2);
            buf[qrow * 68 + l32]             += O00[r];
            buf[qrow * 68 + 32 + l32]        += O01[r];
            buf[(qrow + 32) * 68 + l32]      += O10[r];
            buf[(qrow + 32) * 68 + 32 + l32] += O11[r];
        }
    }
    __syncthreads();
    {
        int q0 = tid >> 3;
        int d0 = (tid & 7) << 3;
        #pragma unroll
        for (int qh = 0; qh < 2; ++qh) {
            int q = q0 + (qh << 5);
            const float* b0 = Obuf[0] + q * 68 + d0;
            const float* b1 = Obuf[1] + q * 68 + d0;
            float* dst = Pout + (((size_t)(bt << 12) + qbase + q) << 6) + d0;
            #pragma unroll
            for (int i = 0; i < 8; ++i) dst[i] = b0[i] + b1[i];
            if ((tid & 7) == 0)
                Lout[(bt << 12) + qbase + q] =
                    l_s[0][q] + l_s[1][q] + l_s[2][q] + l_s[3][q];
        }
    }
}

// ---------------- k_hyper: fused hypernetwork contraction, 16-node tiles ---
// Grid = 512 blocks (256 n-tiles x 2 o-halves), 3 blocks/CU.
// Stage: float4 loads of x / P0+P1 (4x fewer global ops than scalar).
// Inner loop: explicit double-buffered wpB fragment prefetch so the L2
// latency hides under the mfma16 + 48-FMA body of the previous kk.
__global__ __launch_bounds__(256, 3) void k_hyper(const float* __restrict__ x,
                                                  const float* __restrict__ P0,
                                                  const float* __restrict__ P1,
                                                  const float* __restrict__ L0,
                                                  const float* __restrict__ L1,
                                                  const unsigned short* __restrict__ ne_bf,
                                                  const unsigned short* __restrict__ wpB,
                                                  const float* __restrict__ bias_ws,
                                                  float* __restrict__ out) {
    __shared__ float smem[13056];          // 52.2 KB: xg (4x3104) then red (4x3264)
    __shared__ float invl_s[96];
    const int t    = threadIdx.x;
    const int w    = t >> 6;
    const int lane = t & 63;
    const int l16  = lane & 15;
    const int quad = lane >> 4;
    const int n0   = (blockIdx.x >> 1) << 4;
    const int oh   = blockIdx.x & 1;       // o-half

    if (t < 96) {
        int bt = t % 6, nl = t / 6;
        int idx = (bt << 12) + n0 + nl;
        invl_s[t] = 1.f / (L0[idx] + L1[idx]);
    }
    __syncthreads();

    float* xg_s = smem + w * 3104;         // 32 kk x (96 btnl + 1 pad)
    const int i0 = (w & 1) << 5;
    #pragma unroll
    for (int it = 0; it < 12; ++it) {      // 768 float4 per wave region
        int u    = (it << 6) + lane;       // 0..767
        int btnl = u >> 3;                 // 0..95 = nl*6+bt
        int kk4  = (u & 7) << 2;           // 0,4,..,28
        int bt = btnl % 6;
        int nl = btnl / 6;
        size_t idx = (((size_t)(bt << 12) + n0 + nl) << 6) + i0 + kk4;
        f32x4 v;
        if (w < 2) {
            v = *(const f32x4*)(x + idx);
        } else {
            f32x4 p0 = *(const f32x4*)(P0 + idx);
            f32x4 p1 = *(const f32x4*)(P1 + idx);
            float il = invl_s[btnl];
            #pragma unroll
            for (int m = 0; m < 4; ++m) v[m] = (p0[m] + p1[m]) * il;
        }
        #pragma unroll
        for (int m = 0; m < 4; ++m) xg_s[(kk4 + m) * 97 + btnl] = v[m];
    }
    __syncthreads();

    const unsigned short* nb = ne_bf + ((n0 + l16) << 6) + (quad << 3);
    bf16x8 a0 = *(const bf16x8*)(nb);
    bf16x8 a1 = *(const bf16x8*)(nb + 32);

    float oac[2][4][6];
    #pragma unroll
    for (int oc = 0; oc < 2; ++oc)
        #pragma unroll
        for (int r = 0; r < 4; ++r)
            #pragma unroll
            for (int bt = 0; bt < 6; ++bt) oac[oc][r][bt] = 0.f;

    // wpB fragment base for this wave: ki = w*32 + kk; per-kk stride 4096
    // shorts; oc adds 1024; second d-half adds 512.
    const unsigned short* bp = wpB + (((size_t)w) << 17) + (oh << 11) + (lane << 3);

    // prefetch kk = 0
    bf16x8 cb0a = *(const bf16x8*)(bp);
    bf16x8 cb1a = *(const bf16x8*)(bp + 512);
    bf16x8 cb0b = *(const bf16x8*)(bp + 1024);
    bf16x8 cb1b = *(const bf16x8*)(bp + 1536);

    #pragma unroll
    for (int kk = 0; kk < 32; ++kk) {
        bf16x8 nb0a, nb1a, nb0b, nb1b;
        if (kk < 31) {                      // prefetch kk+1 (folds at unroll)
            const unsigned short* np = bp + ((size_t)(kk + 1) << 12);
            nb0a = *(const bf16x8*)(np);
            nb1a = *(const bf16x8*)(np + 512);
            nb0b = *(const bf16x8*)(np + 1024);
            nb1b = *(const bf16x8*)(np + 1536);
        }
        float g[4][6];
        #pragma unroll
        for (int r = 0; r < 4; ++r) {
            const float* gp = xg_s + kk * 97 + ((quad << 2) + r) * 6;
            #pragma unroll
            for (int bt = 0; bt < 6; ++bt) g[r][bt] = gp[bt];
        }
        f32x4 wf0 = mfma16(a0, cb0a, f32x4{0.f, 0.f, 0.f, 0.f});
        wf0 = mfma16(a1, cb1a, wf0);
        f32x4 wf1 = mfma16(a0, cb0b, f32x4{0.f, 0.f, 0.f, 0.f});
        wf1 = mfma16(a1, cb1b, wf1);
        #pragma unroll
        for (int r = 0; r < 4; ++r)
            #pragma unroll
            for (int bt = 0; bt < 6; ++bt) {
                oac[0][r][bt] += wf0[r] * g[r][bt];
                oac[1][r][bt] += wf1[r] * g[r][bt];
            }
        cb0a = nb0a; cb1a = nb1a; cb0b = nb0b; cb1b = nb1b;
    }

    __syncthreads();                        // xg_s dead; smem becomes red
    #pragma unroll
    for (int oc = 0; oc < 2; ++oc)
        #pragma unroll
        for (int r = 0; r < 4; ++r)
            #pragma unroll
            for (int bt = 0; bt < 6; ++bt)
                smem[w * 3264 + ((quad << 2) + r) * 204 + bt * 34 + (oc << 4) + l16]
                    = oac[oc][r][bt];
    __syncthreads();
    #pragma unroll
    for (int rr = 0; rr < 4; ++rr) {
        int nl = (w << 2) + rr;
        #pragma unroll
        for (int bp2 = 0; bp2 < 3; ++bp2) {
            int bt = bp2 * 2 + (lane >> 5);
            int ol = lane & 31;
            int o  = (oh << 5) + ol;
            int a  = nl * 204 + bt * 34 + ol;
            float v = smem[a] + smem[a + 3264] + smem[a + 6528] + smem[a + 9792]
                    + bias_ws[(bt << 6) + o];
            out[(((size_t)(bt << 12) + n0 + nl) << 6) + o] = v;
        }
    }
}

// ---------------------------------------------------------------------------
extern "C" void kernel_launch(void* const* d_in, const int* in_sizes, int n_in,
                              void* d_out, int out_size, void* d_ws, size_t ws_size,
                              hipStream_t stream) {
    const float* x         = (const float*)d_in[0];
    const float* node_emb  = (const float*)d_in[1];
    const float* time_emb  = (const float*)d_in[2];
    const float* wp        = (const float*)d_in[3];
    const float* bias_pool = (const float*)d_in[4];
    const float* gamma     = (const float*)d_in[5];
    const float* beta      = (const float*)d_in[6];
    float* out = (float*)d_out;

    char* wsb = (char*)d_ws;
    unsigned short* eT    = (unsigned short*)(wsb);                  // 3 MB
    unsigned short* vT    = (unsigned short*)(wsb + 3145728);        // 3 MB
    float*          P0    = (float*)         (wsb + 6291456);        // 6.3 MB
    float*          P1    = (float*)         (wsb + 12582912);       // 6.3 MB
    unsigned short* wpB   = (unsigned short*)(wsb + 18874368);       // 1 MB
    unsigned short* ne_bf = (unsigned short*)(wsb + 19922944);       // 0.5 MB
    float*          biasw = (float*)         (wsb + 20447232);       // 1.5 KB
    float*          L0    = (float*)         (wsb + 20448768);       // 96 KB
    float*          L1    = (float*)         (wsb + 20547072);       // 96 KB

    k_prep<<<3073, 256, 0, stream>>>(x, node_emb, time_emb, wp, bias_pool,
                                     gamma, beta, eT, vT, ne_bf, wpB, biasw);
    k_attn<<<768, 256, 0, stream>>>(eT, vT, P0, P1, L0, L1);
    k_hyper<<<512, 256, 0, stream>>>(x, P0, P1, L0, L1, ne_bf, wpB, biasw, out);
}